// Round 8
// baseline (164.807 us; speedup 1.0000x reference)
//
#include <hip/hip_runtime.h>
#include <hip/hip_bf16.h>
#include <stdint.h>

// SelfAttention B=8 H=8 S=2048 D=64 fp32, mask[B,S,S] int32 (0 -> -1e9).
// Round 8: LDS-BW fix — dual q-subtile per wave (32 q-rows) sharing every
// K/V ds_read_b128 (halves LDS read traffic, the measured ~80%-busy pipe).
// 4-wave/256-thr blocks, stage=4 gload_lds/thread, counted vmcnt(4) barriers,
// 4 LDS slots. Keeps: max-free exp2 softmax, mask bias as MFMA C-in, K/V bf16
// + mask-bitpack prepass, ones-column denominator, setprio, XCD swizzle.

#define B_ 8
#define H_ 8
#define S_ 2048
#define D_ 64
#define QT 128
#define KT 64
#define NT (S_ / KT)
#define TILE_E (KT * D_)  // 4096 shorts = 8 KB per K (or V) slot
#define LOG2E 1.44269504088896340736f
#define QSCALE (0.125f * LOG2E)

typedef __bf16 bf16;
typedef bf16 bf16x8 __attribute__((ext_vector_type(8)));
typedef float f32x4 __attribute__((ext_vector_type(4)));
typedef unsigned short ushort8_t __attribute__((ext_vector_type(8)));
typedef unsigned long long u64;

#if __has_builtin(__builtin_amdgcn_exp2f)
#define EXP2(x) __builtin_amdgcn_exp2f(x)
#else
#define EXP2(x) exp2f(x)
#endif

static __device__ __forceinline__ unsigned short bfb(float f) {
    bf16 h = (bf16)f;  // RNE
    return __builtin_bit_cast(unsigned short, h);
}
// kv' bit-permutation: kv bits [b5 b4 b3 b2 b1 b0] -> kv' = [b5 b3 b2 b4 b1 b0].
static __device__ __forceinline__ int phi_inv(int c) {
    return ((c >> 5) & 1) * 32 + ((c >> 2) & 1) * 16 + ((c >> 4) & 1) * 8 +
           ((c >> 3) & 1) * 4 + (c & 3);
}
static __device__ __forceinline__ void gload16(const unsigned short* g, unsigned short* l) {
    __builtin_amdgcn_global_load_lds(
        (const __attribute__((address_space(1))) unsigned int*)g,
        (__attribute__((address_space(3))) unsigned int*)l, 16, 0, 0);
}

#define KV_BLOCKS (B_ * H_ * NT)  // 2048

// Fused prepass: blocks [0, KV_BLOCKS) convert K/V (if Ko != null); rest bitpack mask.
__global__ __launch_bounds__(256) void prep_fused(
    const float* __restrict__ K, const float* __restrict__ V,
    unsigned short* __restrict__ Ko, unsigned short* __restrict__ Vo,
    const int* __restrict__ M, u64* __restrict__ W) {
    const int tid = threadIdx.x;
    if (blockIdx.x >= KV_BLOCKS) {
        const int ln = tid & 63;
        const int w0 = (blockIdx.x - KV_BLOCKS) * 32 + (tid >> 6) * 8;
#pragma unroll
        for (int j = 0; j < 8; ++j) {
            const int v = M[(long)(w0 + j) * 64 + ln];
            const u64 bal = __ballot(v != 0);
            if (ln == 0) W[w0 + j] = bal;
        }
        return;
    }
    if (Ko == nullptr) return;
    __shared__ float Vl[64][65];
    const int t = blockIdx.x & (NT - 1);
    const int bh = blockIdx.x >> 5;
    const float* Kg = K + ((long)bh * S_ + t * 64) * D_;
    const float* Vg = V + ((long)bh * S_ + t * 64) * D_;
    unsigned short* Kout = Ko + ((long)bh * S_ + t * 64) * D_;
    unsigned short* Vout = Vo + (long)bh * D_ * S_ + t * 64;
    {   // K convert: 16 elems/thread
        const int kv = tid >> 2, d0 = (tid & 3) * 16;
#pragma unroll
        for (int half = 0; half < 2; ++half) {
            const float4 f0 = *(const float4*)(Kg + kv * D_ + d0 + half * 8);
            const float4 f1 = *(const float4*)(Kg + kv * D_ + d0 + half * 8 + 4);
            ushort8_t u;
            u[0] = bfb(f0.x); u[1] = bfb(f0.y); u[2] = bfb(f0.z); u[3] = bfb(f0.w);
            u[4] = bfb(f1.x); u[5] = bfb(f1.y); u[6] = bfb(f1.z); u[7] = bfb(f1.w);
            *(ushort8_t*)(Kout + kv * D_ + d0 + half * 8) = u;
        }
    }
    {   // V stage to LDS (coalesced reads)
#pragma unroll
        for (int i = 0; i < 4; ++i) {
            const int kv = i * 16 + (tid >> 4);
            const int d4 = (tid & 15) * 4;
            const float4 f = *(const float4*)(Vg + kv * D_ + d4);
            Vl[kv][d4 + 0] = f.x; Vl[kv][d4 + 1] = f.y;
            Vl[kv][d4 + 2] = f.z; Vl[kv][d4 + 3] = f.w;
        }
    }
    __syncthreads();
    {   // write transposed+permuted, coalesced ushort4 stores
#pragma unroll
        for (int j = 0; j < 4; ++j) {
            const int chunk = j * 256 + tid;
            const int d = chunk >> 4, q4 = chunk & 15;
            ushort4 w;
            w.x = bfb(Vl[phi_inv(q4 * 4 + 0)][d]);
            w.y = bfb(Vl[phi_inv(q4 * 4 + 1)][d]);
            w.z = bfb(Vl[phi_inv(q4 * 4 + 2)][d]);
            w.w = bfb(Vl[phi_inv(q4 * 4 + 3)][d]);
            *(ushort4*)(Vout + (long)d * S_ + q4 * 4) = w;
        }
    }
}

// ---- main kernel: 4 waves x 32 q-rows (two 16-row subtiles sharing K/V reads) ----
__global__ __launch_bounds__(256, 2) void attn_main(
    const float* __restrict__ Q, const u64* __restrict__ W,
    const unsigned short* __restrict__ Kp, const unsigned short* __restrict__ Vp,
    float* __restrict__ O)
{
    __shared__ __attribute__((aligned(16))) unsigned short Ks3[4 * TILE_E];  // 32 KB
    __shared__ __attribute__((aligned(16))) unsigned short Vt3[4 * TILE_E];  // 32 KB

    const int tid = threadIdx.x;
    const int wv = tid >> 6, ln = tid & 63;
    const int col = ln & 15, grp = ln >> 4;

    int bid = blockIdx.x;
    bid = (bid & 7) * 128 + (bid >> 3);  // XCD chunk swizzle (1024 % 8 == 0, bijective)
    const int qt = bid & 15;
    const int h = (bid >> 4) & 7;
    const int b = bid >> 7;
    const int qa = qt * QT + wv * 32;    // subtile a: rows qa..qa+15; b: qa+16..qa+31

    // Q frags (B-operand) for both subtiles, prescaled
    bf16x8 qfa[2], qfb[2];
    {
        const float* Qga = Q + ((long)((b * H_ + h) * S_) + qa + col) * D_;
        const float* Qgb = Qga + 16 * D_;
#pragma unroll
        for (int c = 0; c < 2; ++c) {
            const float4 a0 = *(const float4*)(Qga + c * 32 + grp * 8);
            const float4 a1 = *(const float4*)(Qga + c * 32 + grp * 8 + 4);
            qfa[c][0] = (bf16)(a0.x * QSCALE); qfa[c][1] = (bf16)(a0.y * QSCALE);
            qfa[c][2] = (bf16)(a0.z * QSCALE); qfa[c][3] = (bf16)(a0.w * QSCALE);
            qfa[c][4] = (bf16)(a1.x * QSCALE); qfa[c][5] = (bf16)(a1.y * QSCALE);
            qfa[c][6] = (bf16)(a1.z * QSCALE); qfa[c][7] = (bf16)(a1.w * QSCALE);
            const float4 b0 = *(const float4*)(Qgb + c * 32 + grp * 8);
            const float4 b1 = *(const float4*)(Qgb + c * 32 + grp * 8 + 4);
            qfb[c][0] = (bf16)(b0.x * QSCALE); qfb[c][1] = (bf16)(b0.y * QSCALE);
            qfb[c][2] = (bf16)(b0.z * QSCALE); qfb[c][3] = (bf16)(b0.w * QSCALE);
            qfb[c][4] = (bf16)(b1.x * QSCALE); qfb[c][5] = (bf16)(b1.y * QSCALE);
            qfb[c][6] = (bf16)(b1.z * QSCALE); qfb[c][7] = (bf16)(b1.w * QSCALE);
        }
    }
    bf16x8 onesf;
#pragma unroll
    for (int j = 0; j < 8; ++j) onesf[j] = (bf16)1.0f;

    f32x4 oaccA[4], oaccB[4];
#pragma unroll
    for (int i = 0; i < 4; ++i) {
        oaccA[i] = (f32x4){0.f, 0.f, 0.f, 0.f};
        oaccB[i] = (f32x4){0.f, 0.f, 0.f, 0.f};
    }
    f32x4 accsA = (f32x4){0.f, 0.f, 0.f, 0.f};
    f32x4 accsB = (f32x4){0.f, 0.f, 0.f, 0.f};

    const u64* Wa = W + ((long)b * S_ + qa + col) * (S_ / 64);
    const u64* Wb = Wa + 16 * (S_ / 64);
    const unsigned short* Kbh = Kp + (long)(b * H_ + h) * S_ * D_;
    const unsigned short* Vbh = Vp + (long)(b * H_ + h) * D_ * S_;

    // gload addressing: inverse-swizzled global source, linear LDS dest.
    // 256 threads x 2 chunks cover 64 rows: row = i*32 + wv*8 + (ln>>3).
    const int rl = ln >> 3;
    const int c8 = (ln & 7) ^ rl;  // (row & 7) == rl for all i, wv

    auto STAGE_ISSUE = [&](int kv0, int buf) {  // 4 gload_lds/thread
#pragma unroll
        for (int i = 0; i < 2; ++i) {
            const int row = i * 32 + wv * 8 + rl;
            gload16(Kbh + (long)(kv0 + row) * D_ + c8 * 8,
                    Ks3 + buf * TILE_E + i * 2048 + wv * 512);
            gload16(Vbh + (long)row * S_ + kv0 + c8 * 8,
                    Vt3 + buf * TILE_E + i * 2048 + wv * 512);
        }
    };

    auto STEP = [&](u64 mwa, u64 mwb, const unsigned short* Kc, const unsigned short* Vc) {
        // mask bias as MFMA C-in: 0 or -1e9
        f32x4 sa[4], sb[4];
        {
            const u64 ma = mwa >> (grp * 4), mb = mwb >> (grp * 4);
            const unsigned alo = (unsigned)ma, ahi = (unsigned)(ma >> 32);
            const unsigned blo = (unsigned)mb, bhi = (unsigned)(mb >> 32);
#pragma unroll
            for (int blk = 0; blk < 4; ++blk) {
                const unsigned wa32 = (blk < 2) ? alo : ahi;
                const unsigned wb32 = (blk < 2) ? blo : bhi;
#pragma unroll
                for (int r = 0; r < 4; ++r) {
                    const int bit = (blk & 1) * 16 + r;  // compile-time
                    sa[blk][r] = ((wa32 >> bit) & 1u) ? 0.0f : -1e9f;
                    sb[blk][r] = ((wb32 >> bit) & 1u) ? 0.0f : -1e9f;
                }
            }
        }
        // QK^T swapped, K-frags read ONCE and used by both subtiles
        __builtin_amdgcn_s_setprio(1);
#pragma unroll
        for (int blk = 0; blk < 4; ++blk) {
            const int row = blk * 16 + col;
            const int byte0 = (row * 128 + grp * 16) ^ ((row & 7) << 4);
            const int byte1 = (row * 128 + 64 + grp * 16) ^ ((row & 7) << 4);
            const bf16x8 kf0 = *(const bf16x8*)((const char*)Kc + byte0);
            const bf16x8 kf1 = *(const bf16x8*)((const char*)Kc + byte1);
            sa[blk] = __builtin_amdgcn_mfma_f32_16x16x32_bf16(kf0, qfa[0], sa[blk], 0, 0, 0);
            sa[blk] = __builtin_amdgcn_mfma_f32_16x16x32_bf16(kf1, qfa[1], sa[blk], 0, 0, 0);
            sb[blk] = __builtin_amdgcn_mfma_f32_16x16x32_bf16(kf0, qfb[0], sb[blk], 0, 0, 0);
            sb[blk] = __builtin_amdgcn_mfma_f32_16x16x32_bf16(kf1, qfb[1], sb[blk], 0, 0, 0);
        }
        __builtin_amdgcn_s_setprio(0);
        // exp2 + bf16 pack (no max subtraction; masked -> 0)
        bf16x8 pa[2], pb[2];
#pragma unroll
        for (int c = 0; c < 2; ++c)
#pragma unroll
            for (int j = 0; j < 8; ++j) {
                const int blk = 2 * c + (j >> 2), r = j & 3;
                pa[c][j] = (bf16)EXP2(sa[blk][r]);
                pb[c][j] = (bf16)EXP2(sb[blk][r]);
            }
        // denominators + PV; V-frags read ONCE, used by both subtiles
        __builtin_amdgcn_s_setprio(1);
        accsA = __builtin_amdgcn_mfma_f32_16x16x32_bf16(pa[0], onesf, accsA, 0, 0, 0);
        accsA = __builtin_amdgcn_mfma_f32_16x16x32_bf16(pa[1], onesf, accsA, 0, 0, 0);
        accsB = __builtin_amdgcn_mfma_f32_16x16x32_bf16(pb[0], onesf, accsB, 0, 0, 0);
        accsB = __builtin_amdgcn_mfma_f32_16x16x32_bf16(pb[1], onesf, accsB, 0, 0, 0);
#pragma unroll
        for (int c = 0; c < 2; ++c)
#pragma unroll
            for (int db = 0; db < 4; ++db) {
                const int vrow = db * 16 + col;
                const int byte = (vrow * 128 + c * 64 + grp * 16) ^ ((vrow & 7) << 4);
                const bf16x8 vf = *(const bf16x8*)((const char*)Vc + byte);
                oaccA[db] = __builtin_amdgcn_mfma_f32_16x16x32_bf16(pa[c], vf, oaccA[db], 0, 0, 0);
                oaccB[db] = __builtin_amdgcn_mfma_f32_16x16x32_bf16(pb[c], vf, oaccB[db], 0, 0, 0);
            }
        __builtin_amdgcn_s_setprio(0);
    };

#define WAIT4_BAR() do { asm volatile("s_waitcnt vmcnt(4)" ::: "memory"); \
    __builtin_amdgcn_s_barrier(); __builtin_amdgcn_sched_barrier(0); } while (0)
#define WAIT0_BAR() do { asm volatile("s_waitcnt vmcnt(0)" ::: "memory"); \
    __builtin_amdgcn_s_barrier(); __builtin_amdgcn_sched_barrier(0); } while (0)

    // prologue: stage tiles 0,1
    STAGE_ISSUE(0, 0);
    STAGE_ISSUE(KT, 1);
    WAIT4_BAR();  // tile 0 ready (tile 1 may be in flight)

#pragma unroll 1
    for (int tt = 0; tt < NT - 4; tt += 4) {  // t = 0 .. 27
#pragma unroll
        for (int j = 0; j < 4; ++j) {
            const int t = tt + j;
            const u64 mwa = Wa[t], mwb = Wb[t];
            STAGE_ISSUE((t + 2) * KT, (j + 2) & 3);
            STEP(mwa, mwb, Ks3 + j * TILE_E, Vt3 + j * TILE_E);
            WAIT4_BAR();  // tile t+1 ready; t+2 stays in flight
        }
    }
    {   // tail: t = 28..31 (slots 0..3)
        {
            const u64 mwa = Wa[NT - 4], mwb = Wb[NT - 4];
            STAGE_ISSUE((NT - 2) * KT, (NT - 2) & 3);
            STEP(mwa, mwb, Ks3 + ((NT - 4) & 3) * TILE_E, Vt3 + ((NT - 4) & 3) * TILE_E);
            WAIT4_BAR();
        }
        {
            const u64 mwa = Wa[NT - 3], mwb = Wb[NT - 3];
            STAGE_ISSUE((NT - 1) * KT, (NT - 1) & 3);
            STEP(mwa, mwb, Ks3 + ((NT - 3) & 3) * TILE_E, Vt3 + ((NT - 3) & 3) * TILE_E);
            WAIT4_BAR();
        }
        {
            const u64 mwa = Wa[NT - 2], mwb = Wb[NT - 2];
            STEP(mwa, mwb, Ks3 + ((NT - 2) & 3) * TILE_E, Vt3 + ((NT - 2) & 3) * TILE_E);
            WAIT0_BAR();
        }
        {
            const u64 mwa = Wa[NT - 1], mwb = Wb[NT - 1];
            STEP(mwa, mwb, Ks3 + ((NT - 1) & 3) * TILE_E, Vt3 + ((NT - 1) & 3) * TILE_E);
        }
    }

    // epilogue
    float* Oa = O + ((long)((b * H_ + h) * S_) + qa) * D_;
#pragma unroll
    for (int r = 0; r < 4; ++r) {
        const float ia = 1.0f / accsA[r];
        const float ib = 1.0f / accsB[r];
#pragma unroll
        for (int db = 0; db < 4; ++db) {
            Oa[(grp * 4 + r) * D_ + db * 16 + col] = oaccA[db][r] * ia;
            Oa[(16 + grp * 4 + r) * D_ + db * 16 + col] = oaccB[db][r] * ib;
        }
    }
#undef WAIT4_BAR
#undef WAIT0_BAR
}

// ---- fallback kernel (512 thr, 16 q/wave, reg-staging, __syncthreads) ----
template <int MODE>
__global__ __launch_bounds__(512, 4) void attn_fb(
    const float* __restrict__ Q, const float* __restrict__ K,
    const float* __restrict__ V, const int* __restrict__ M,
    const u64* __restrict__ W, float* __restrict__ O)
{
    __shared__ __attribute__((aligned(16))) unsigned short Ks2[2 * TILE_E];
    __shared__ __attribute__((aligned(16))) unsigned short Vt2[2 * TILE_E];

    const int tid = threadIdx.x;
    const int wv = tid >> 6, ln = tid & 63;
    const int col = ln & 15, grp = ln >> 4;

    int bid = blockIdx.x;
    bid = (bid & 7) * 128 + (bid >> 3);
    const int qt = bid & 15;
    const int h = (bid >> 4) & 7;
    const int b = bid >> 7;
    const int qw = qt * QT + wv * 16;

    const float* Qg = Q + ((long)((b * H_ + h) * S_) + qw + col) * D_;
    bf16x8 qf[2];
#pragma unroll
    for (int c = 0; c < 2; ++c) {
        const float4 a0 = *(const float4*)(Qg + c * 32 + grp * 8);
        const float4 a1 = *(const float4*)(Qg + c * 32 + grp * 8 + 4);
        qf[c][0] = (bf16)(a0.x * QSCALE); qf[c][1] = (bf16)(a0.y * QSCALE);
        qf[c][2] = (bf16)(a0.z * QSCALE); qf[c][3] = (bf16)(a0.w * QSCALE);
        qf[c][4] = (bf16)(a1.x * QSCALE); qf[c][5] = (bf16)(a1.y * QSCALE);
        qf[c][6] = (bf16)(a1.z * QSCALE); qf[c][7] = (bf16)(a1.w * QSCALE);
    }
    bf16x8 onesf;
#pragma unroll
    for (int j = 0; j < 8; ++j) onesf[j] = (bf16)1.0f;

    f32x4 oacc[4];
#pragma unroll
    for (int i = 0; i < 4; ++i) oacc[i] = (f32x4){0.f, 0.f, 0.f, 0.f};
    f32x4 accs = (f32x4){0.f, 0.f, 0.f, 0.f};

    const u64* Wg = (MODE >= 1) ? (W + ((long)b * S_ + qw + col) * (S_ / 64)) : nullptr;
    const int* Mg = (MODE == 0) ? (M + ((long)b * S_ + qw + col) * S_) : nullptr;
    const float* Kf = K + (long)(b * H_ + h) * S_ * D_;
    const float* Vf = V + (long)(b * H_ + h) * S_ * D_;

    float4 ka[2];
    float va[8];
    const int vd = ln, kg0 = wv;

    auto LOADT = [&](int kv0) {
#pragma unroll
        for (int i = 0; i < 2; ++i) {
            const int idx4 = i * 512 + tid;
            const int row = idx4 >> 4, c4 = idx4 & 15;
            ka[i] = *(const float4*)(Kf + (long)(kv0 + row) * D_ + c4 * 4);
        }
#pragma unroll
        for (int i = 0; i < 2; ++i) {
            const int kg = kg0 + i * 8;
            const int kvn = phi_inv(kg * 4);
#pragma unroll
            for (int j = 0; j < 4; ++j)
                va[i * 4 + j] = Vf[(long)(kv0 + kvn + j) * D_ + vd];
        }
    };
    auto WRITET = [&](int buf) {
#pragma unroll
        for (int i = 0; i < 2; ++i) {
            const int idx4 = i * 512 + tid;
            const int row = idx4 >> 4, c4 = idx4 & 15;
            const int byte = (row * 128 + c4 * 8) ^ ((row & 7) << 4);
            ushort4 w;
            w.x = bfb(ka[i].x); w.y = bfb(ka[i].y);
            w.z = bfb(ka[i].z); w.w = bfb(ka[i].w);
            *(ushort4*)((char*)(Ks2 + buf * TILE_E) + byte) = w;
        }
#pragma unroll
        for (int i = 0; i < 2; ++i) {
            const int kg = kg0 + i * 8;
            const int byte = (vd * 128 + kg * 8) ^ ((vd & 7) << 4);
            ushort4 w;
            w.x = bfb(va[i * 4 + 0]); w.y = bfb(va[i * 4 + 1]);
            w.z = bfb(va[i * 4 + 2]); w.w = bfb(va[i * 4 + 3]);
            *(ushort4*)((char*)(Vt2 + buf * TILE_E) + byte) = w;
        }
    };
    auto FSTEP = [&](u64 mwfull, int t, const unsigned short* Kc, const unsigned short* Vc) {
        f32x4 sc[4];
        const f32x4 zq = (f32x4){0.f, 0.f, 0.f, 0.f};
#pragma unroll
        for (int blk = 0; blk < 4; ++blk) {
            const int row = blk * 16 + col;
            const int byte0 = (row * 128 + grp * 16) ^ ((row & 7) << 4);
            const int byte1 = (row * 128 + 64 + grp * 16) ^ ((row & 7) << 4);
            const bf16x8 kf0 = *(const bf16x8*)((const char*)Kc + byte0);
            const bf16x8 kf1 = *(const bf16x8*)((const char*)Kc + byte1);
            sc[blk] = __builtin_amdgcn_mfma_f32_16x16x32_bf16(kf0, qf[0], zq, 0, 0, 0);
            sc[blk] = __builtin_amdgcn_mfma_f32_16x16x32_bf16(kf1, qf[1], sc[blk], 0, 0, 0);
        }
        bf16x8 pf[2];
        if (MODE >= 1) {
            const u64 mws = mwfull >> (grp * 4);
            const unsigned mlo = (unsigned)mws, mhi = (unsigned)(mws >> 32);
#pragma unroll
            for (int c = 0; c < 2; ++c)
#pragma unroll
                for (int j = 0; j < 8; ++j) {
                    const int blk = 2 * c + (j >> 2), r = j & 3;
                    const unsigned w32 = (blk < 2) ? mlo : mhi;
                    const int bit = (blk & 1) * 16 + r;
                    const float s = ((w32 >> bit) & 1u) ? sc[blk][r] : -1e9f;
                    pf[c][j] = (bf16)EXP2(s);
                }
        } else {
#pragma unroll
            for (int c = 0; c < 2; ++c)
#pragma unroll
                for (int j = 0; j < 8; ++j) {
                    const int blk = 2 * c + (j >> 2), r = j & 3;
                    const int mv = Mg[t * KT + blk * 16 + grp * 4 + r];
                    const float s = mv ? sc[blk][r] : -1e9f;
                    pf[c][j] = (bf16)EXP2(s);
                }
        }
        accs = __builtin_amdgcn_mfma_f32_16x16x32_bf16(pf[0], onesf, accs, 0, 0, 0);
        accs = __builtin_amdgcn_mfma_f32_16x16x32_bf16(pf[1], onesf, accs, 0, 0, 0);
#pragma unroll
        for (int c = 0; c < 2; ++c)
#pragma unroll
            for (int db = 0; db < 4; ++db) {
                const int vrow = db * 16 + col;
                const int byte = (vrow * 128 + c * 64 + grp * 16) ^ ((vrow & 7) << 4);
                const bf16x8 vf = *(const bf16x8*)((const char*)Vc + byte);
                oacc[db] = __builtin_amdgcn_mfma_f32_16x16x32_bf16(pf[c], vf, oacc[db], 0, 0, 0);
            }
    };

    LOADT(0);
    WRITET(0);
    __syncthreads();
#pragma unroll 1
    for (int t = 0; t < NT; t += 2) {
        if (t + 1 < NT) LOADT((t + 1) * KT);
        FSTEP(MODE >= 1 ? Wg[t] : 0ull, t, Ks2, Vt2);
        if (t + 1 < NT) WRITET(1);
        __syncthreads();
        if (t + 2 < NT) LOADT((t + 2) * KT);
        FSTEP(MODE >= 1 ? Wg[t + 1] : 0ull, t + 1, Ks2 + TILE_E, Vt2 + TILE_E);
        if (t + 2 < NT) WRITET(0);
        __syncthreads();
    }

    float* Og = O + ((long)((b * H_ + h) * S_) + qw) * D_;
#pragma unroll
    for (int r = 0; r < 4; ++r) {
        const float inv = 1.0f / accs[r];
#pragma unroll
        for (int db = 0; db < 4; ++db)
            Og[(grp * 4 + r) * D_ + db * 16 + col] = oacc[db][r] * inv;
    }
}

extern "C" void kernel_launch(void* const* d_in, const int* in_sizes, int n_in,
                              void* d_out, int out_size, void* d_ws, size_t ws_size,
                              hipStream_t stream) {
    (void)in_sizes; (void)n_in; (void)out_size;
    const float* Q = (const float*)d_in[0];
    const float* K = (const float*)d_in[1];
    const float* V = (const float*)d_in[2];
    const int*   M = (const int*)d_in[3];
    float* O = (float*)d_out;

    const size_t szW = (size_t)B_ * S_ * (S_ / 64) * sizeof(u64);      // 4 MB
    const size_t szK = (size_t)B_ * H_ * S_ * D_ * 2;                  // 16 MB
    const int grid = B_ * H_ * (S_ / QT);                              // 1024
    const int nmaskblk = (B_ * S_ * (S_ / 64)) / 32;                   // 16384

    if (ws_size >= szW + 2 * szK) {
        u64* W = (u64*)d_ws;
        unsigned short* Kp = (unsigned short*)((char*)d_ws + szW);
        unsigned short* Vp = (unsigned short*)((char*)d_ws + szW + szK);
        prep_fused<<<KV_BLOCKS + nmaskblk, 256, 0, stream>>>(K, V, Kp, Vp, M, W);
        attn_main<<<grid, 256, 0, stream>>>(Q, W, Kp, Vp, O);
    } else if (ws_size >= szW) {
        u64* W = (u64*)d_ws;
        prep_fused<<<KV_BLOCKS + nmaskblk, 256, 0, stream>>>(K, V, nullptr, nullptr, M, W);
        attn_fb<1><<<grid, 512, 0, stream>>>(Q, K, V, M, W, O);
    } else {
        attn_fb<0><<<grid, 512, 0, stream>>>(Q, K, V, M, nullptr, O);
    }
}

// Round 9
// 155.834 us; speedup vs baseline: 1.0576x; 1.0576x over previous
//
#include <hip/hip_runtime.h>
#include <hip/hip_bf16.h>
#include <stdint.h>

// SelfAttention B=8 H=8 S=2048 D=64 fp32, mask[B,S,S] int32 (0 -> -1e9).
// Round 9: QT=256 — 8 waves x 32 q-rows (dual subtile) per 512-thread block.
// Keeps R8's halved LDS-read traffic (K/V frags shared by 2 subtiles) while
// restoring 16 waves/CU (512 blocks = exactly 2/CU, LDS-capped). Staging is
// now 2 gload_lds/thread (vmcnt(2) counted waits). Keeps: max-free exp2
// softmax, mask bias as MFMA C-in, K/V bf16 + mask-bitpack prepass,
// ones-column denominator, setprio, XCD swizzle, 4 LDS slots.

#define B_ 8
#define H_ 8
#define S_ 2048
#define D_ 64
#define QT 256  // q rows per block: 8 waves x 32
#define KT 64
#define NT (S_ / KT)
#define TILE_E (KT * D_)  // 4096 shorts = 8 KB per K (or V) slot
#define LOG2E 1.44269504088896340736f
#define QSCALE (0.125f * LOG2E)

typedef __bf16 bf16;
typedef bf16 bf16x8 __attribute__((ext_vector_type(8)));
typedef float f32x4 __attribute__((ext_vector_type(4)));
typedef unsigned short ushort8_t __attribute__((ext_vector_type(8)));
typedef unsigned long long u64;

#if __has_builtin(__builtin_amdgcn_exp2f)
#define EXP2(x) __builtin_amdgcn_exp2f(x)
#else
#define EXP2(x) exp2f(x)
#endif

static __device__ __forceinline__ unsigned short bfb(float f) {
    bf16 h = (bf16)f;  // RNE
    return __builtin_bit_cast(unsigned short, h);
}
// kv' bit-permutation: kv bits [b5 b4 b3 b2 b1 b0] -> kv' = [b5 b3 b2 b4 b1 b0].
static __device__ __forceinline__ int phi_inv(int c) {
    return ((c >> 5) & 1) * 32 + ((c >> 2) & 1) * 16 + ((c >> 4) & 1) * 8 +
           ((c >> 3) & 1) * 4 + (c & 3);
}
static __device__ __forceinline__ void gload16(const unsigned short* g, unsigned short* l) {
    __builtin_amdgcn_global_load_lds(
        (const __attribute__((address_space(1))) unsigned int*)g,
        (__attribute__((address_space(3))) unsigned int*)l, 16, 0, 0);
}

#define KV_BLOCKS (B_ * H_ * NT)  // 2048

// Fused prepass: blocks [0, KV_BLOCKS) convert K/V (if Ko != null); rest bitpack mask.
__global__ __launch_bounds__(256) void prep_fused(
    const float* __restrict__ K, const float* __restrict__ V,
    unsigned short* __restrict__ Ko, unsigned short* __restrict__ Vo,
    const int* __restrict__ M, u64* __restrict__ W) {
    const int tid = threadIdx.x;
    if (blockIdx.x >= KV_BLOCKS) {
        const int ln = tid & 63;
        const int w0 = (blockIdx.x - KV_BLOCKS) * 32 + (tid >> 6) * 8;
#pragma unroll
        for (int j = 0; j < 8; ++j) {
            const int v = M[(long)(w0 + j) * 64 + ln];
            const u64 bal = __ballot(v != 0);
            if (ln == 0) W[w0 + j] = bal;
        }
        return;
    }
    if (Ko == nullptr) return;
    __shared__ float Vl[64][65];
    const int t = blockIdx.x & (NT - 1);
    const int bh = blockIdx.x >> 5;
    const float* Kg = K + ((long)bh * S_ + t * 64) * D_;
    const float* Vg = V + ((long)bh * S_ + t * 64) * D_;
    unsigned short* Kout = Ko + ((long)bh * S_ + t * 64) * D_;
    unsigned short* Vout = Vo + (long)bh * D_ * S_ + t * 64;
    {   // K convert: 16 elems/thread
        const int kv = tid >> 2, d0 = (tid & 3) * 16;
#pragma unroll
        for (int half = 0; half < 2; ++half) {
            const float4 f0 = *(const float4*)(Kg + kv * D_ + d0 + half * 8);
            const float4 f1 = *(const float4*)(Kg + kv * D_ + d0 + half * 8 + 4);
            ushort8_t u;
            u[0] = bfb(f0.x); u[1] = bfb(f0.y); u[2] = bfb(f0.z); u[3] = bfb(f0.w);
            u[4] = bfb(f1.x); u[5] = bfb(f1.y); u[6] = bfb(f1.z); u[7] = bfb(f1.w);
            *(ushort8_t*)(Kout + kv * D_ + d0 + half * 8) = u;
        }
    }
    {   // V stage to LDS (coalesced reads)
#pragma unroll
        for (int i = 0; i < 4; ++i) {
            const int kv = i * 16 + (tid >> 4);
            const int d4 = (tid & 15) * 4;
            const float4 f = *(const float4*)(Vg + kv * D_ + d4);
            Vl[kv][d4 + 0] = f.x; Vl[kv][d4 + 1] = f.y;
            Vl[kv][d4 + 2] = f.z; Vl[kv][d4 + 3] = f.w;
        }
    }
    __syncthreads();
    {   // write transposed+permuted, coalesced ushort4 stores
#pragma unroll
        for (int j = 0; j < 4; ++j) {
            const int chunk = j * 256 + tid;
            const int d = chunk >> 4, q4 = chunk & 15;
            ushort4 w;
            w.x = bfb(Vl[phi_inv(q4 * 4 + 0)][d]);
            w.y = bfb(Vl[phi_inv(q4 * 4 + 1)][d]);
            w.z = bfb(Vl[phi_inv(q4 * 4 + 2)][d]);
            w.w = bfb(Vl[phi_inv(q4 * 4 + 3)][d]);
            *(ushort4*)(Vout + (long)d * S_ + q4 * 4) = w;
        }
    }
}

// ---- main kernel: 8 waves x 32 q-rows (two 16-row subtiles sharing K/V reads) ----
__global__ __launch_bounds__(512, 4) void attn_main(
    const float* __restrict__ Q, const u64* __restrict__ W,
    const unsigned short* __restrict__ Kp, const unsigned short* __restrict__ Vp,
    float* __restrict__ O)
{
    __shared__ __attribute__((aligned(16))) unsigned short Ks3[4 * TILE_E];  // 32 KB
    __shared__ __attribute__((aligned(16))) unsigned short Vt3[4 * TILE_E];  // 32 KB

    const int tid = threadIdx.x;
    const int wv = tid >> 6, ln = tid & 63;
    const int col = ln & 15, grp = ln >> 4;

    int bid = blockIdx.x;
    bid = (bid & 7) * 64 + (bid >> 3);   // XCD chunk swizzle (512 % 8 == 0, bijective)
    const int qt = bid & 7;              // 8 q-tiles of 256 rows
    const int h = (bid >> 3) & 7;
    const int b = bid >> 6;
    const int qa = qt * QT + wv * 32;    // subtile a: rows qa..qa+15; b: qa+16..qa+31

    // Q frags (B-operand) for both subtiles, prescaled
    bf16x8 qfa[2], qfb[2];
    {
        const float* Qga = Q + ((long)((b * H_ + h) * S_) + qa + col) * D_;
        const float* Qgb = Qga + 16 * D_;
#pragma unroll
        for (int c = 0; c < 2; ++c) {
            const float4 a0 = *(const float4*)(Qga + c * 32 + grp * 8);
            const float4 a1 = *(const float4*)(Qga + c * 32 + grp * 8 + 4);
            qfa[c][0] = (bf16)(a0.x * QSCALE); qfa[c][1] = (bf16)(a0.y * QSCALE);
            qfa[c][2] = (bf16)(a0.z * QSCALE); qfa[c][3] = (bf16)(a0.w * QSCALE);
            qfa[c][4] = (bf16)(a1.x * QSCALE); qfa[c][5] = (bf16)(a1.y * QSCALE);
            qfa[c][6] = (bf16)(a1.z * QSCALE); qfa[c][7] = (bf16)(a1.w * QSCALE);
            const float4 b0 = *(const float4*)(Qgb + c * 32 + grp * 8);
            const float4 b1 = *(const float4*)(Qgb + c * 32 + grp * 8 + 4);
            qfb[c][0] = (bf16)(b0.x * QSCALE); qfb[c][1] = (bf16)(b0.y * QSCALE);
            qfb[c][2] = (bf16)(b0.z * QSCALE); qfb[c][3] = (bf16)(b0.w * QSCALE);
            qfb[c][4] = (bf16)(b1.x * QSCALE); qfb[c][5] = (bf16)(b1.y * QSCALE);
            qfb[c][6] = (bf16)(b1.z * QSCALE); qfb[c][7] = (bf16)(b1.w * QSCALE);
        }
    }
    bf16x8 onesf;
#pragma unroll
    for (int j = 0; j < 8; ++j) onesf[j] = (bf16)1.0f;

    f32x4 oaccA[4], oaccB[4];
#pragma unroll
    for (int i = 0; i < 4; ++i) {
        oaccA[i] = (f32x4){0.f, 0.f, 0.f, 0.f};
        oaccB[i] = (f32x4){0.f, 0.f, 0.f, 0.f};
    }
    f32x4 accsA = (f32x4){0.f, 0.f, 0.f, 0.f};
    f32x4 accsB = (f32x4){0.f, 0.f, 0.f, 0.f};

    const u64* Wa = W + ((long)b * S_ + qa + col) * (S_ / 64);
    const u64* Wb = Wa + 16 * (S_ / 64);
    const unsigned short* Kbh = Kp + (long)(b * H_ + h) * S_ * D_;
    const unsigned short* Vbh = Vp + (long)(b * H_ + h) * D_ * S_;

    // gload addressing: 512 threads cover 64 rows x 128 B; linear LDS dest,
    // inverse-swizzled global source.
    const int srow = tid >> 3;            // 0..63
    const int rl = srow & 7;
    const int c8 = (tid & 7) ^ rl;

    auto STAGE_ISSUE = [&](int kv0, int buf) {  // 2 gload_lds/thread
        gload16(Kbh + (long)(kv0 + srow) * D_ + c8 * 8, Ks3 + buf * TILE_E + tid * 8);
        gload16(Vbh + (long)srow * S_ + kv0 + c8 * 8, Vt3 + buf * TILE_E + tid * 8);
    };

    auto STEP = [&](u64 mwa, u64 mwb, const unsigned short* Kc, const unsigned short* Vc) {
        // mask bias as MFMA C-in: 0 or -1e9
        f32x4 sa[4], sb[4];
        {
            const u64 ma = mwa >> (grp * 4), mb = mwb >> (grp * 4);
            const unsigned alo = (unsigned)ma, ahi = (unsigned)(ma >> 32);
            const unsigned blo = (unsigned)mb, bhi = (unsigned)(mb >> 32);
#pragma unroll
            for (int blk = 0; blk < 4; ++blk) {
                const unsigned wa32 = (blk < 2) ? alo : ahi;
                const unsigned wb32 = (blk < 2) ? blo : bhi;
#pragma unroll
                for (int r = 0; r < 4; ++r) {
                    const int bit = (blk & 1) * 16 + r;  // compile-time
                    sa[blk][r] = ((wa32 >> bit) & 1u) ? 0.0f : -1e9f;
                    sb[blk][r] = ((wb32 >> bit) & 1u) ? 0.0f : -1e9f;
                }
            }
        }
        // QK^T swapped, K-frags read ONCE and used by both subtiles
        __builtin_amdgcn_s_setprio(1);
#pragma unroll
        for (int blk = 0; blk < 4; ++blk) {
            const int row = blk * 16 + col;
            const int byte0 = (row * 128 + grp * 16) ^ ((row & 7) << 4);
            const int byte1 = (row * 128 + 64 + grp * 16) ^ ((row & 7) << 4);
            const bf16x8 kf0 = *(const bf16x8*)((const char*)Kc + byte0);
            const bf16x8 kf1 = *(const bf16x8*)((const char*)Kc + byte1);
            sa[blk] = __builtin_amdgcn_mfma_f32_16x16x32_bf16(kf0, qfa[0], sa[blk], 0, 0, 0);
            sa[blk] = __builtin_amdgcn_mfma_f32_16x16x32_bf16(kf1, qfa[1], sa[blk], 0, 0, 0);
            sb[blk] = __builtin_amdgcn_mfma_f32_16x16x32_bf16(kf0, qfb[0], sb[blk], 0, 0, 0);
            sb[blk] = __builtin_amdgcn_mfma_f32_16x16x32_bf16(kf1, qfb[1], sb[blk], 0, 0, 0);
        }
        __builtin_amdgcn_s_setprio(0);
        // exp2 + bf16 pack (no max subtraction; masked -> 0)
        bf16x8 pa[2], pb[2];
#pragma unroll
        for (int c = 0; c < 2; ++c)
#pragma unroll
            for (int j = 0; j < 8; ++j) {
                const int blk = 2 * c + (j >> 2), r = j & 3;
                pa[c][j] = (bf16)EXP2(sa[blk][r]);
                pb[c][j] = (bf16)EXP2(sb[blk][r]);
            }
        // denominators + PV; V-frags read ONCE, used by both subtiles
        __builtin_amdgcn_s_setprio(1);
        accsA = __builtin_amdgcn_mfma_f32_16x16x32_bf16(pa[0], onesf, accsA, 0, 0, 0);
        accsA = __builtin_amdgcn_mfma_f32_16x16x32_bf16(pa[1], onesf, accsA, 0, 0, 0);
        accsB = __builtin_amdgcn_mfma_f32_16x16x32_bf16(pb[0], onesf, accsB, 0, 0, 0);
        accsB = __builtin_amdgcn_mfma_f32_16x16x32_bf16(pb[1], onesf, accsB, 0, 0, 0);
#pragma unroll
        for (int c = 0; c < 2; ++c)
#pragma unroll
            for (int db = 0; db < 4; ++db) {
                const int vrow = db * 16 + col;
                const int byte = (vrow * 128 + c * 64 + grp * 16) ^ ((vrow & 7) << 4);
                const bf16x8 vf = *(const bf16x8*)((const char*)Vc + byte);
                oaccA[db] = __builtin_amdgcn_mfma_f32_16x16x32_bf16(pa[c], vf, oaccA[db], 0, 0, 0);
                oaccB[db] = __builtin_amdgcn_mfma_f32_16x16x32_bf16(pb[c], vf, oaccB[db], 0, 0, 0);
            }
        __builtin_amdgcn_s_setprio(0);
    };

#define WAIT2_BAR() do { asm volatile("s_waitcnt vmcnt(2)" ::: "memory"); \
    __builtin_amdgcn_s_barrier(); __builtin_amdgcn_sched_barrier(0); } while (0)
#define WAIT0_BAR() do { asm volatile("s_waitcnt vmcnt(0)" ::: "memory"); \
    __builtin_amdgcn_s_barrier(); __builtin_amdgcn_sched_barrier(0); } while (0)

    // prologue: stage tiles 0,1
    STAGE_ISSUE(0, 0);
    STAGE_ISSUE(KT, 1);
    WAIT2_BAR();  // tile 0 ready (tile 1 may be in flight)

#pragma unroll 1
    for (int tt = 0; tt < NT - 4; tt += 4) {  // t = 0 .. 27
#pragma unroll
        for (int j = 0; j < 4; ++j) {
            const int t = tt + j;
            const u64 mwa = Wa[t], mwb = Wb[t];
            STAGE_ISSUE((t + 2) * KT, (j + 2) & 3);
            STEP(mwa, mwb, Ks3 + j * TILE_E, Vt3 + j * TILE_E);
            WAIT2_BAR();  // tile t+1 ready; t+2 stays in flight
        }
    }
    {   // tail: t = 28..31 (slots 0..3)
        {
            const u64 mwa = Wa[NT - 4], mwb = Wb[NT - 4];
            STAGE_ISSUE((NT - 2) * KT, (NT - 2) & 3);
            STEP(mwa, mwb, Ks3 + ((NT - 4) & 3) * TILE_E, Vt3 + ((NT - 4) & 3) * TILE_E);
            WAIT2_BAR();
        }
        {
            const u64 mwa = Wa[NT - 3], mwb = Wb[NT - 3];
            STAGE_ISSUE((NT - 1) * KT, (NT - 1) & 3);
            STEP(mwa, mwb, Ks3 + ((NT - 3) & 3) * TILE_E, Vt3 + ((NT - 3) & 3) * TILE_E);
            WAIT2_BAR();
        }
        {
            const u64 mwa = Wa[NT - 2], mwb = Wb[NT - 2];
            STEP(mwa, mwb, Ks3 + ((NT - 2) & 3) * TILE_E, Vt3 + ((NT - 2) & 3) * TILE_E);
            WAIT0_BAR();
        }
        {
            const u64 mwa = Wa[NT - 1], mwb = Wb[NT - 1];
            STEP(mwa, mwb, Ks3 + ((NT - 1) & 3) * TILE_E, Vt3 + ((NT - 1) & 3) * TILE_E);
        }
    }

    // epilogue
    float* Oa = O + ((long)((b * H_ + h) * S_) + qa) * D_;
#pragma unroll
    for (int r = 0; r < 4; ++r) {
        const float ia = 1.0f / accsA[r];
        const float ib = 1.0f / accsB[r];
#pragma unroll
        for (int db = 0; db < 4; ++db) {
            Oa[(grp * 4 + r) * D_ + db * 16 + col] = oaccA[db][r] * ia;
            Oa[(16 + grp * 4 + r) * D_ + db * 16 + col] = oaccB[db][r] * ib;
        }
    }
#undef WAIT2_BAR
#undef WAIT0_BAR
}

// ---- fallback kernel (512 thr, 16 q/wave, reg-staging, __syncthreads) ----
template <int MODE>
__global__ __launch_bounds__(512, 4) void attn_fb(
    const float* __restrict__ Q, const float* __restrict__ K,
    const float* __restrict__ V, const int* __restrict__ M,
    const u64* __restrict__ W, float* __restrict__ O)
{
    __shared__ __attribute__((aligned(16))) unsigned short Ks2[2 * TILE_E];
    __shared__ __attribute__((aligned(16))) unsigned short Vt2[2 * TILE_E];

    const int tid = threadIdx.x;
    const int wv = tid >> 6, ln = tid & 63;
    const int col = ln & 15, grp = ln >> 4;

    int bid = blockIdx.x;
    bid = (bid & 7) * 128 + (bid >> 3);
    const int qt = bid & 15;
    const int h = (bid >> 4) & 7;
    const int b = bid >> 7;
    const int qw = qt * 128 + wv * 16;

    const float* Qg = Q + ((long)((b * H_ + h) * S_) + qw + col) * D_;
    bf16x8 qf[2];
#pragma unroll
    for (int c = 0; c < 2; ++c) {
        const float4 a0 = *(const float4*)(Qg + c * 32 + grp * 8);
        const float4 a1 = *(const float4*)(Qg + c * 32 + grp * 8 + 4);
        qf[c][0] = (bf16)(a0.x * QSCALE); qf[c][1] = (bf16)(a0.y * QSCALE);
        qf[c][2] = (bf16)(a0.z * QSCALE); qf[c][3] = (bf16)(a0.w * QSCALE);
        qf[c][4] = (bf16)(a1.x * QSCALE); qf[c][5] = (bf16)(a1.y * QSCALE);
        qf[c][6] = (bf16)(a1.z * QSCALE); qf[c][7] = (bf16)(a1.w * QSCALE);
    }
    bf16x8 onesf;
#pragma unroll
    for (int j = 0; j < 8; ++j) onesf[j] = (bf16)1.0f;

    f32x4 oacc[4];
#pragma unroll
    for (int i = 0; i < 4; ++i) oacc[i] = (f32x4){0.f, 0.f, 0.f, 0.f};
    f32x4 accs = (f32x4){0.f, 0.f, 0.f, 0.f};

    const u64* Wg = (MODE >= 1) ? (W + ((long)b * S_ + qw + col) * (S_ / 64)) : nullptr;
    const int* Mg = (MODE == 0) ? (M + ((long)b * S_ + qw + col) * S_) : nullptr;
    const float* Kf = K + (long)(b * H_ + h) * S_ * D_;
    const float* Vf = V + (long)(b * H_ + h) * S_ * D_;

    float4 ka[2];
    float va[8];
    const int vd = ln, kg0 = wv;

    auto LOADT = [&](int kv0) {
#pragma unroll
        for (int i = 0; i < 2; ++i) {
            const int idx4 = i * 512 + tid;
            const int row = idx4 >> 4, c4 = idx4 & 15;
            ka[i] = *(const float4*)(Kf + (long)(kv0 + row) * D_ + c4 * 4);
        }
#pragma unroll
        for (int i = 0; i < 2; ++i) {
            const int kg = kg0 + i * 8;
            const int kvn = phi_inv(kg * 4);
#pragma unroll
            for (int j = 0; j < 4; ++j)
                va[i * 4 + j] = Vf[(long)(kv0 + kvn + j) * D_ + vd];
        }
    };
    auto WRITET = [&](int buf) {
#pragma unroll
        for (int i = 0; i < 2; ++i) {
            const int idx4 = i * 512 + tid;
            const int row = idx4 >> 4, c4 = idx4 & 15;
            const int byte = (row * 128 + c4 * 8) ^ ((row & 7) << 4);
            ushort4 w;
            w.x = bfb(ka[i].x); w.y = bfb(ka[i].y);
            w.z = bfb(ka[i].z); w.w = bfb(ka[i].w);
            *(ushort4*)((char*)(Ks2 + buf * TILE_E) + byte) = w;
        }
#pragma unroll
        for (int i = 0; i < 2; ++i) {
            const int kg = kg0 + i * 8;
            const int byte = (vd * 128 + kg * 8) ^ ((vd & 7) << 4);
            ushort4 w;
            w.x = bfb(va[i * 4 + 0]); w.y = bfb(va[i * 4 + 1]);
            w.z = bfb(va[i * 4 + 2]); w.w = bfb(va[i * 4 + 3]);
            *(ushort4*)((char*)(Vt2 + buf * TILE_E) + byte) = w;
        }
    };
    auto FSTEP = [&](u64 mwfull, int t, const unsigned short* Kc, const unsigned short* Vc) {
        f32x4 sc[4];
        const f32x4 zq = (f32x4){0.f, 0.f, 0.f, 0.f};
#pragma unroll
        for (int blk = 0; blk < 4; ++blk) {
            const int row = blk * 16 + col;
            const int byte0 = (row * 128 + grp * 16) ^ ((row & 7) << 4);
            const int byte1 = (row * 128 + 64 + grp * 16) ^ ((row & 7) << 4);
            const bf16x8 kf0 = *(const bf16x8*)((const char*)Kc + byte0);
            const bf16x8 kf1 = *(const bf16x8*)((const char*)Kc + byte1);
            sc[blk] = __builtin_amdgcn_mfma_f32_16x16x32_bf16(kf0, qf[0], zq, 0, 0, 0);
            sc[blk] = __builtin_amdgcn_mfma_f32_16x16x32_bf16(kf1, qf[1], sc[blk], 0, 0, 0);
        }
        bf16x8 pf[2];
        if (MODE >= 1) {
            const u64 mws = mwfull >> (grp * 4);
            const unsigned mlo = (unsigned)mws, mhi = (unsigned)(mws >> 32);
#pragma unroll
            for (int c = 0; c < 2; ++c)
#pragma unroll
                for (int j = 0; j < 8; ++j) {
                    const int blk = 2 * c + (j >> 2), r = j & 3;
                    const unsigned w32 = (blk < 2) ? mlo : mhi;
                    const int bit = (blk & 1) * 16 + r;
                    const float s = ((w32 >> bit) & 1u) ? sc[blk][r] : -1e9f;
                    pf[c][j] = (bf16)EXP2(s);
                }
        } else {
#pragma unroll
            for (int c = 0; c < 2; ++c)
#pragma unroll
                for (int j = 0; j < 8; ++j) {
                    const int blk = 2 * c + (j >> 2), r = j & 3;
                    const int mv = Mg[t * KT + blk * 16 + grp * 4 + r];
                    const float s = mv ? sc[blk][r] : -1e9f;
                    pf[c][j] = (bf16)EXP2(s);
                }
        }
        accs = __builtin_amdgcn_mfma_f32_16x16x32_bf16(pf[0], onesf, accs, 0, 0, 0);
        accs = __builtin_amdgcn_mfma_f32_16x16x32_bf16(pf[1], onesf, accs, 0, 0, 0);
#pragma unroll
        for (int c = 0; c < 2; ++c)
#pragma unroll
            for (int db = 0; db < 4; ++db) {
                const int vrow = db * 16 + col;
                const int byte = (vrow * 128 + c * 64 + grp * 16) ^ ((vrow & 7) << 4);
                const bf16x8 vf = *(const bf16x8*)((const char*)Vc + byte);
                oacc[db] = __builtin_amdgcn_mfma_f32_16x16x32_bf16(pf[c], vf, oacc[db], 0, 0, 0);
            }
    };

    LOADT(0);
    WRITET(0);
    __syncthreads();
#pragma unroll 1
    for (int t = 0; t < NT; t += 2) {
        if (t + 1 < NT) LOADT((t + 1) * KT);
        FSTEP(MODE >= 1 ? Wg[t] : 0ull, t, Ks2, Vt2);
        if (t + 1 < NT) WRITET(1);
        __syncthreads();
        if (t + 2 < NT) LOADT((t + 2) * KT);
        FSTEP(MODE >= 1 ? Wg[t + 1] : 0ull, t + 1, Ks2 + TILE_E, Vt2 + TILE_E);
        if (t + 2 < NT) WRITET(0);
        __syncthreads();
    }

    float* Og = O + ((long)((b * H_ + h) * S_) + qw) * D_;
#pragma unroll
    for (int r = 0; r < 4; ++r) {
        const float inv = 1.0f / accs[r];
#pragma unroll
        for (int db = 0; db < 4; ++db)
            Og[(grp * 4 + r) * D_ + db * 16 + col] = oacc[db][r] * inv;
    }
}

extern "C" void kernel_launch(void* const* d_in, const int* in_sizes, int n_in,
                              void* d_out, int out_size, void* d_ws, size_t ws_size,
                              hipStream_t stream) {
    (void)in_sizes; (void)n_in; (void)out_size;
    const float* Q = (const float*)d_in[0];
    const float* K = (const float*)d_in[1];
    const float* V = (const float*)d_in[2];
    const int*   M = (const int*)d_in[3];
    float* O = (float*)d_out;

    const size_t szW = (size_t)B_ * S_ * (S_ / 64) * sizeof(u64);      // 4 MB
    const size_t szK = (size_t)B_ * H_ * S_ * D_ * 2;                  // 16 MB
    const int nmaskblk = (B_ * S_ * (S_ / 64)) / 32;                   // 16384

    if (ws_size >= szW + 2 * szK) {
        u64* W = (u64*)d_ws;
        unsigned short* Kp = (unsigned short*)((char*)d_ws + szW);
        unsigned short* Vp = (unsigned short*)((char*)d_ws + szW + szK);
        prep_fused<<<KV_BLOCKS + nmaskblk, 256, 0, stream>>>(K, V, Kp, Vp, M, W);
        attn_main<<<B_ * H_ * (S_ / QT), 512, 0, stream>>>(Q, W, Kp, Vp, O);  // 512 blocks
    } else if (ws_size >= szW) {
        u64* W = (u64*)d_ws;
        prep_fused<<<KV_BLOCKS + nmaskblk, 256, 0, stream>>>(K, V, nullptr, nullptr, M, W);
        attn_fb<1><<<1024, 512, 0, stream>>>(Q, K, V, M, W, O);
    } else {
        attn_fb<0><<<1024, 512, 0, stream>>>(Q, K, V, M, nullptr, O);
    }
}